// Round 8
// baseline (940.762 us; speedup 1.0000x reference)
//
#include <hip/hip_runtime.h>

#define HID 128
#define BR  128        // GEMM rows per block
#define FILL_CHUNK 2048

typedef _Float16 f16;
typedef f16 f16x2 __attribute__((ext_vector_type(2)));
typedef f16 f16x4 __attribute__((ext_vector_type(4)));
typedef f16 f16x8 __attribute__((ext_vector_type(8)));
typedef float f32x4 __attribute__((ext_vector_type(4)));

static __device__ __forceinline__ float2 h2f(unsigned int u) {
    f16x2 v;
    __builtin_memcpy(&v, &u, 4);
    return make_float2((float)v[0], (float)v[1]);
}

// ================= degree / CSR build =================

__global__ void k_deg_count(const int* __restrict__ col, int* __restrict__ cnt, int E) {
    int e = blockIdx.x * 256 + threadIdx.x;
    if (e < E) atomicAdd(&cnt[col[e]], 1);
}

__global__ void k_scan_block(const int* __restrict__ cnt, int* __restrict__ excl,
                             int* __restrict__ bsum, float* __restrict__ dinv, int N) {
    __shared__ int s[256];
    int i = blockIdx.x * 256 + threadIdx.x;
    int v = (i < N) ? cnt[i] : 0;
    if (i < N) dinv[i] = 1.0f / sqrtf((float)(v + 1));   // +1 = self-loop
    s[threadIdx.x] = v;
    __syncthreads();
    for (int off = 1; off < 256; off <<= 1) {
        int t = (threadIdx.x >= off) ? s[threadIdx.x - off] : 0;
        __syncthreads();
        s[threadIdx.x] += t;
        __syncthreads();
    }
    if (i < N) excl[i] = s[threadIdx.x] - v;
    if (threadIdx.x == 255) bsum[blockIdx.x] = s[255];
}

__global__ __launch_bounds__(1024) void k_scan_bsum(int* __restrict__ bsum, int nb) {
    __shared__ int s[1024];
    int i = threadIdx.x;
    int v = (i < nb) ? bsum[i] : 0;
    s[i] = v;
    __syncthreads();
    for (int off = 1; off < 1024; off <<= 1) {
        int t = (i >= off) ? s[i - off] : 0;
        __syncthreads();
        s[i] += t;
        __syncthreads();
    }
    if (i < nb) bsum[i] = s[i] - v;
}

__global__ void k_scan_add(int* __restrict__ row_ptr, const int* __restrict__ bsum,
                           int* __restrict__ fill, int N, int E) {
    int i = blockIdx.x * 256 + threadIdx.x;
    if (i < N) {
        int v = row_ptr[i] + bsum[blockIdx.x];
        row_ptr[i] = v;
        fill[i] = v;
    }
    if (i == 0) row_ptr[N] = E;
}

// XCD-range-filtered scatter: block b -> edge chunk (b>>3), col-range (b&7).
__global__ void k_fill(const int* __restrict__ row, const int* __restrict__ col,
                       int* __restrict__ fill, int* __restrict__ csr_src, int E, int N) {
    const int xcd = blockIdx.x & 7;
    const int chunk = blockIdx.x >> 3;
    const int per = (N + 7) >> 3;
    const int lo = xcd * per;
    const int hi = min(N, lo + per);
    const int eend = min(E, (chunk + 1) * FILL_CHUNK);
    for (int e = chunk * FILL_CHUNK + threadIdx.x; e < eend; e += 256) {
        int c = col[e];
        if (c >= lo && c < hi) {
            int p = atomicAdd(&fill[c], 1);
            csr_src[p] = row[e];
        }
    }
}

// ================= W prep: transpose + f16 hi/lo split =================
// element (k,n) -> (k>>3)*1024 + n*8 + (k&7); hi [0,16384), lo [16384,32768)

__global__ void k_wprep(const float* __restrict__ W, f16* __restrict__ out) {
    int i = blockIdx.x * 256 + threadIdx.x;   // 4096 float4s
    if (i >= 4096) return;
    int k = i >> 5, n0 = (i & 31) * 4;
    float4 v = reinterpret_cast<const float4*>(W)[i];
    float vv[4] = {v.x, v.y, v.z, v.w};
#pragma unroll
    for (int e = 0; e < 4; ++e) {
        int n = n0 + e;
        int idx = (k >> 3) * 1024 + n * 8 + (k & 7);
        f16 h = (f16)vv[e];
        out[idx] = h;
        out[16384 + idx] = (f16)(vv[e] - (float)h);
    }
}

// ================= GEMM: H16 = f16( dinv .* (act(X) @ W) )  via split-f16 MFMA =================

__global__ __launch_bounds__(512, 4) void k_gemm(const float* __restrict__ X,
                                                 const f16* __restrict__ Wt,
                                                 const float* __restrict__ dinv,
                                                 f16* __restrict__ H,
                                                 int N, int relu_in) {
    __shared__ f16 Xs[2 * 16384];   // 64 KB: hi [0,16384), lo [16384,)
    const int t = threadIdx.x;
    const int row0 = blockIdx.x * BR;

    const int w  = t >> 6;
    const int l  = t & 63;
    const int lg = l >> 4;
    const int li = l & 15;
    const int rg = w >> 2;          // 0..1
    const int cg = w & 3;           // 0..3

    // B fragments from global, issued before X staging (latency hidden)
    f16x8 Bh[2][4], Bl[2][4];
#pragma unroll
    for (int cb = 0; cb < 2; ++cb) {
        const int ncol = cg * 32 + cb * 16 + li;
#pragma unroll
        for (int ks = 0; ks < 4; ++ks) {
            const int idx = (ks * 4 + lg) * 1024 + ncol * 8;
            Bh[cb][ks] = *reinterpret_cast<const f16x8*>(&Wt[idx]);
            Bl[cb][ks] = *reinterpret_cast<const f16x8*>(&Wt[16384 + idx]);
        }
    }

    // stage X tile: ReLU + hi/lo split + 16B-chunk swizzle
    for (int i = t; i < 4096; i += 512) {
        int r = i >> 5, q = i & 31;
        int gr = row0 + r;
        float4 v = make_float4(0.f, 0.f, 0.f, 0.f);
        if (gr < N) {
            v = reinterpret_cast<const float4*>(X + (size_t)gr * HID)[q];
            if (relu_in) {
                v.x = fmaxf(v.x, 0.f); v.y = fmaxf(v.y, 0.f);
                v.z = fmaxf(v.z, 0.f); v.w = fmaxf(v.w, 0.f);
            }
        }
        f16 h0 = (f16)v.x, h1 = (f16)v.y, h2 = (f16)v.z, h3 = (f16)v.w;
        f16 l0 = (f16)(v.x - (float)h0), l1 = (f16)(v.y - (float)h1);
        f16 l2 = (f16)(v.z - (float)h2), l3 = (f16)(v.w - (float)h3);
        int base = r * 128 + (((q >> 1) ^ (r & 7)) * 8) + (q & 1) * 4;
        *reinterpret_cast<f16x4*>(&Xs[base])         = (f16x4){h0, h1, h2, h3};
        *reinterpret_cast<f16x4*>(&Xs[16384 + base]) = (f16x4){l0, l1, l2, l3};
    }
    __syncthreads();

    f32x4 acc[4][2];
#pragma unroll
    for (int rb = 0; rb < 4; ++rb)
#pragma unroll
        for (int cb = 0; cb < 2; ++cb) acc[rb][cb] = (f32x4){0.f, 0.f, 0.f, 0.f};

#pragma unroll
    for (int rb = 0; rb < 4; ++rb) {
        const int arow = rg * 64 + rb * 16 + li;
#pragma unroll
        for (int ks = 0; ks < 4; ++ks) {
            const int idx = arow * 128 + (((ks * 4 + lg) ^ (arow & 7)) * 8);
            f16x8 Ah = *reinterpret_cast<const f16x8*>(&Xs[idx]);
            f16x8 Al = *reinterpret_cast<const f16x8*>(&Xs[16384 + idx]);
#pragma unroll
            for (int cb = 0; cb < 2; ++cb) {
                acc[rb][cb] = __builtin_amdgcn_mfma_f32_16x16x32_f16(Ah, Bh[cb][ks], acc[rb][cb], 0, 0, 0);
                acc[rb][cb] = __builtin_amdgcn_mfma_f32_16x16x32_f16(Ah, Bl[cb][ks], acc[rb][cb], 0, 0, 0);
                acc[rb][cb] = __builtin_amdgcn_mfma_f32_16x16x32_f16(Al, Bh[cb][ks], acc[rb][cb], 0, 0, 0);
            }
        }
    }

    // epilogue: D col = lane&15, row = (lane>>4)*4 + reg; scale by dinv, store f16
#pragma unroll
    for (int rb = 0; rb < 4; ++rb) {
#pragma unroll
        for (int r = 0; r < 4; ++r) {
            const int grow = row0 + rg * 64 + rb * 16 + lg * 4 + r;
            if (grow < N) {
                const float d = dinv[grow];
#pragma unroll
                for (int cb = 0; cb < 2; ++cb)
                    H[(size_t)grow * HID + cg * 32 + cb * 16 + li] = (f16)(acc[rb][cb][r] * d);
            }
        }
    }
}

// ================= aggregation: XCD column-split gather =================
// Block b: column group g=b&7 (8 uints = 16 cols), node chunk b>>3 (32 nodes).
// Grid is a multiple of 8 -> round-robin dispatch pins group g to XCD g, whose
// h column-slice (N x 32 B = 3.2 MB) is L2-resident. csr_src/out are streamed
// non-temporally so they don't evict the h slice.

__global__ __launch_bounds__(256) void k_agg_csr(const f16* __restrict__ h,
                                                 const int* __restrict__ csr_src,
                                                 const int* __restrict__ row_ptr,
                                                 const float* __restrict__ dinv,
                                                 const float* __restrict__ bias,
                                                 float* __restrict__ out, int N) {
    const int g    = blockIdx.x & 7;
    const int node = (blockIdx.x >> 3) * 32 + (threadIdx.x >> 3);
    if (node >= N) return;
    const int r    = threadIdx.x & 7;
    const int colu = g * 8 + r;                 // uint column 0..63
    const unsigned int* h32 = reinterpret_cast<const unsigned int*>(h);

    float2 self = h2f(h32[(size_t)node * 64 + colu]);
    float accx = self.x, accy = self.y;

    int j = row_ptr[node];
    const int end = row_ptr[node + 1];

    for (; j + 4 <= end; j += 4) {
        int s0 = __builtin_nontemporal_load(csr_src + j);
        int s1 = __builtin_nontemporal_load(csr_src + j + 1);
        int s2 = __builtin_nontemporal_load(csr_src + j + 2);
        int s3 = __builtin_nontemporal_load(csr_src + j + 3);
        unsigned int u0 = h32[(size_t)s0 * 64 + colu];
        unsigned int u1 = h32[(size_t)s1 * 64 + colu];
        unsigned int u2 = h32[(size_t)s2 * 64 + colu];
        unsigned int u3 = h32[(size_t)s3 * 64 + colu];
        float2 v0 = h2f(u0), v1 = h2f(u1), v2 = h2f(u2), v3 = h2f(u3);
        accx += (v0.x + v1.x) + (v2.x + v3.x);
        accy += (v0.y + v1.y) + (v2.y + v3.y);
    }
    for (; j < end; ++j) {
        int s = __builtin_nontemporal_load(csr_src + j);
        float2 v = h2f(h32[(size_t)s * 64 + colu]);
        accx += v.x;
        accy += v.y;
    }

    const float di = dinv[node];
    const int c = colu * 2;
    __builtin_nontemporal_store(fmaf(di, accx, bias[c]),     out + (size_t)node * HID + c);
    __builtin_nontemporal_store(fmaf(di, accy, bias[c + 1]), out + (size_t)node * HID + c + 1);
}

// ================= launch =================

extern "C" void kernel_launch(void* const* d_in, const int* in_sizes, int n_in,
                              void* d_out, int out_size, void* d_ws, size_t ws_size,
                              hipStream_t stream) {
    const float* x  = (const float*)d_in[0];
    const int*   ei = (const int*)  d_in[1];
    const float* W0 = (const float*)d_in[2];
    const float* b0 = (const float*)d_in[3];
    const float* W1 = (const float*)d_in[4];
    const float* b1 = (const float*)d_in[5];
    const float* W2 = (const float*)d_in[6];
    const float* b2 = (const float*)d_in[7];

    const int N = in_sizes[0] / HID;
    const int E = in_sizes[1] / 2;
    const int* row = ei;        // sources
    const int* col = ei + E;    // destinations

    const int nb_n = (N + 255) / 256;

    // workspace layout
    f16*   h16     = (f16*)d_ws;                      // [N,128] f16 (= h', dinv-scaled)
    float* dinv    = (float*)(h16 + (size_t)N * HID); // [N]
    int*   cnt     = (int*)(dinv + N);                // [N]
    int*   row_ptr = cnt + N;                         // [N+1]
    int*   fill    = row_ptr + (N + 1);               // [N]
    int*   bsum    = fill + N;                        // [nb_n]
    int*   csr_src = bsum + nb_n;                     // [E]
    f16*   wt0     = (f16*)(csr_src + E);             // [32768] each
    f16*   wt1     = wt0 + 32768;
    f16*   wt2     = wt1 + 32768;
    float* out     = (float*)d_out;                   // [N,128]

    const int nb_e    = (E + 255) / 256;
    const int nb_gemm = (N + BR - 1) / BR;
    const int nb_agg  = ((N + 31) / 32) * 8;          // %8 == 0 -> group g pins to XCD g
    const int nb_fill = ((E + FILL_CHUNK - 1) / FILL_CHUNK) * 8;

    // ---- CSR build + W prep ----
    hipMemsetAsync(cnt, 0, (size_t)N * sizeof(int), stream);
    k_wprep<<<16, 256, 0, stream>>>(W0, wt0);
    k_wprep<<<16, 256, 0, stream>>>(W1, wt1);
    k_wprep<<<16, 256, 0, stream>>>(W2, wt2);
    k_deg_count <<<nb_e, 256, 0, stream>>>(col, cnt, E);
    k_scan_block<<<nb_n, 256, 0, stream>>>(cnt, row_ptr, bsum, dinv, N);
    k_scan_bsum <<<1, 1024, 0, stream>>>(bsum, nb_n);
    k_scan_add  <<<nb_n, 256, 0, stream>>>(row_ptr, bsum, fill, N, E);
    k_fill      <<<nb_fill, 256, 0, stream>>>(row, col, fill, csr_src, E, N);

    // ---- layer 0 ----
    k_gemm   <<<nb_gemm, 512, 0, stream>>>(x, wt0, dinv, h16, N, 0);
    k_agg_csr<<<nb_agg, 256, 0, stream>>>(h16, csr_src, row_ptr, dinv, b0, out, N);
    // ---- layer 1 ----
    k_gemm   <<<nb_gemm, 512, 0, stream>>>(out, wt1, dinv, h16, N, 1);
    k_agg_csr<<<nb_agg, 256, 0, stream>>>(h16, csr_src, row_ptr, dinv, b1, out, N);
    // ---- layer 2 ----
    k_gemm   <<<nb_gemm, 512, 0, stream>>>(out, wt2, dinv, h16, N, 1);
    k_agg_csr<<<nb_agg, 256, 0, stream>>>(h16, csr_src, row_ptr, dinv, b2, out, N);
}

// Round 9
// 455.518 us; speedup vs baseline: 2.0653x; 2.0653x over previous
//
#include <hip/hip_runtime.h>

#define HID 128
#define BR  128        // GEMM rows per block
#define FILL_CHUNK 2048

typedef _Float16 f16;
typedef f16 f16x2 __attribute__((ext_vector_type(2)));
typedef f16 f16x4 __attribute__((ext_vector_type(4)));
typedef f16 f16x8 __attribute__((ext_vector_type(8)));
typedef float f32x4 __attribute__((ext_vector_type(4)));

static __device__ __forceinline__ float2 h2f(unsigned int u) {
    f16x2 v;
    __builtin_memcpy(&v, &u, 4);
    return make_float2((float)v[0], (float)v[1]);
}

// ================= degree / CSR build =================

__global__ void k_deg_count(const int* __restrict__ col, int* __restrict__ cnt, int E) {
    int e = blockIdx.x * 256 + threadIdx.x;
    if (e < E) atomicAdd(&cnt[col[e]], 1);
}

__global__ void k_scan_block(const int* __restrict__ cnt, int* __restrict__ excl,
                             int* __restrict__ bsum, float* __restrict__ dinv, int N) {
    __shared__ int s[256];
    int i = blockIdx.x * 256 + threadIdx.x;
    int v = (i < N) ? cnt[i] : 0;
    if (i < N) dinv[i] = 1.0f / sqrtf((float)(v + 1));   // +1 = self-loop
    s[threadIdx.x] = v;
    __syncthreads();
    for (int off = 1; off < 256; off <<= 1) {
        int t = (threadIdx.x >= off) ? s[threadIdx.x - off] : 0;
        __syncthreads();
        s[threadIdx.x] += t;
        __syncthreads();
    }
    if (i < N) excl[i] = s[threadIdx.x] - v;
    if (threadIdx.x == 255) bsum[blockIdx.x] = s[255];
}

__global__ __launch_bounds__(1024) void k_scan_bsum(int* __restrict__ bsum, int nb) {
    __shared__ int s[1024];
    int i = threadIdx.x;
    int v = (i < nb) ? bsum[i] : 0;
    s[i] = v;
    __syncthreads();
    for (int off = 1; off < 1024; off <<= 1) {
        int t = (i >= off) ? s[i - off] : 0;
        __syncthreads();
        s[i] += t;
        __syncthreads();
    }
    if (i < nb) bsum[i] = s[i] - v;
}

__global__ void k_scan_add(int* __restrict__ row_ptr, const int* __restrict__ bsum,
                           int* __restrict__ fill, int N, int E) {
    int i = blockIdx.x * 256 + threadIdx.x;
    if (i < N) {
        int v = row_ptr[i] + bsum[blockIdx.x];
        row_ptr[i] = v;
        fill[i] = v;
    }
    if (i == 0) row_ptr[N] = E;
}

// XCD-range-filtered scatter: block b -> edge chunk (b>>3), col-range (b&7).
__global__ void k_fill(const int* __restrict__ row, const int* __restrict__ col,
                       int* __restrict__ fill, int* __restrict__ csr_src, int E, int N) {
    const int xcd = blockIdx.x & 7;
    const int chunk = blockIdx.x >> 3;
    const int per = (N + 7) >> 3;
    const int lo = xcd * per;
    const int hi = min(N, lo + per);
    const int eend = min(E, (chunk + 1) * FILL_CHUNK);
    for (int e = chunk * FILL_CHUNK + threadIdx.x; e < eend; e += 256) {
        int c = col[e];
        if (c >= lo && c < hi) {
            int p = atomicAdd(&fill[c], 1);
            csr_src[p] = row[e];
        }
    }
}

// ================= W prep: transpose + f16 hi/lo split =================
// element (k,n) -> (k>>3)*1024 + n*8 + (k&7); hi [0,16384), lo [16384,32768)

__global__ void k_wprep(const float* __restrict__ W, f16* __restrict__ out) {
    int i = blockIdx.x * 256 + threadIdx.x;   // 4096 float4s
    if (i >= 4096) return;
    int k = i >> 5, n0 = (i & 31) * 4;
    float4 v = reinterpret_cast<const float4*>(W)[i];
    float vv[4] = {v.x, v.y, v.z, v.w};
#pragma unroll
    for (int e = 0; e < 4; ++e) {
        int n = n0 + e;
        int idx = (k >> 3) * 1024 + n * 8 + (k & 7);
        f16 h = (f16)vv[e];
        out[idx] = h;
        out[16384 + idx] = (f16)(vv[e] - (float)h);
    }
}

// ================= GEMM: H16 = f16( dinv .* (act(X) @ W) ) =================
// MODE 0: f32 input, no relu, 3-limb split-f16 (xh*wh + xh*wl + xl*wh), 64 KB LDS.
// MODE 1: f16 input (exact), relu, 2-limb (x*wh + x*wl), 32 KB LDS.

template<int MODE>
__global__ __launch_bounds__(512, 4) void k_gemm(const void* __restrict__ Xv,
                                                 const f16* __restrict__ Wt,
                                                 const float* __restrict__ dinv,
                                                 f16* __restrict__ H, int N) {
    __shared__ f16 Xs[MODE == 0 ? 2 * 16384 : 16384];
    const int t = threadIdx.x;
    const int row0 = blockIdx.x * BR;

    const int w  = t >> 6;
    const int l  = t & 63;
    const int lg = l >> 4;
    const int li = l & 15;
    const int rg = w >> 2;          // 0..1
    const int cg = w & 3;           // 0..3

    // B fragments from global, issued before X staging (latency hidden)
    f16x8 Bh[2][4], Bl[2][4];
#pragma unroll
    for (int cb = 0; cb < 2; ++cb) {
        const int ncol = cg * 32 + cb * 16 + li;
#pragma unroll
        for (int ks = 0; ks < 4; ++ks) {
            const int idx = (ks * 4 + lg) * 1024 + ncol * 8;
            Bh[cb][ks] = *reinterpret_cast<const f16x8*>(&Wt[idx]);
            Bl[cb][ks] = *reinterpret_cast<const f16x8*>(&Wt[16384 + idx]);
        }
    }

    if constexpr (MODE == 0) {
        // f32 input: ReLU none, hi/lo split, 16B-chunk swizzle
        const float* X = (const float*)Xv;
        for (int i = t; i < 4096; i += 512) {
            int r = i >> 5, q = i & 31;
            int gr = row0 + r;
            float4 v = make_float4(0.f, 0.f, 0.f, 0.f);
            if (gr < N) v = reinterpret_cast<const float4*>(X + (size_t)gr * HID)[q];
            f16 h0 = (f16)v.x, h1 = (f16)v.y, h2 = (f16)v.z, h3 = (f16)v.w;
            f16 l0 = (f16)(v.x - (float)h0), l1 = (f16)(v.y - (float)h1);
            f16 l2 = (f16)(v.z - (float)h2), l3 = (f16)(v.w - (float)h3);
            int base = r * 128 + (((q >> 1) ^ (r & 7)) * 8) + (q & 1) * 4;
            *reinterpret_cast<f16x4*>(&Xs[base])         = (f16x4){h0, h1, h2, h3};
            *reinterpret_cast<f16x4*>(&Xs[16384 + base]) = (f16x4){l0, l1, l2, l3};
        }
    } else {
        // f16 input: relu, straight copy, 16B-chunk swizzle (2048 chunks)
        const f16* X = (const f16*)Xv;
        for (int i = t; i < 2048; i += 512) {
            int r = i >> 4, q = i & 15;
            int gr = row0 + r;
            f16x8 v = {};
            if (gr < N) v = *reinterpret_cast<const f16x8*>(X + (size_t)gr * HID + q * 8);
#pragma unroll
            for (int e = 0; e < 8; ++e) v[e] = v[e] > (f16)0 ? v[e] : (f16)0;
            *reinterpret_cast<f16x8*>(&Xs[r * 128 + ((q ^ (r & 7)) * 8)]) = v;
        }
    }
    __syncthreads();

    f32x4 acc[4][2];
#pragma unroll
    for (int rb = 0; rb < 4; ++rb)
#pragma unroll
        for (int cb = 0; cb < 2; ++cb) acc[rb][cb] = (f32x4){0.f, 0.f, 0.f, 0.f};

#pragma unroll
    for (int rb = 0; rb < 4; ++rb) {
        const int arow = rg * 64 + rb * 16 + li;
#pragma unroll
        for (int ks = 0; ks < 4; ++ks) {
            const int idx = arow * 128 + (((ks * 4 + lg) ^ (arow & 7)) * 8);
            f16x8 Ah = *reinterpret_cast<const f16x8*>(&Xs[idx]);
#pragma unroll
            for (int cb = 0; cb < 2; ++cb) {
                acc[rb][cb] = __builtin_amdgcn_mfma_f32_16x16x32_f16(Ah, Bh[cb][ks], acc[rb][cb], 0, 0, 0);
                acc[rb][cb] = __builtin_amdgcn_mfma_f32_16x16x32_f16(Ah, Bl[cb][ks], acc[rb][cb], 0, 0, 0);
            }
            if constexpr (MODE == 0) {
                f16x8 Al = *reinterpret_cast<const f16x8*>(&Xs[16384 + idx]);
#pragma unroll
                for (int cb = 0; cb < 2; ++cb)
                    acc[rb][cb] = __builtin_amdgcn_mfma_f32_16x16x32_f16(Al, Bh[cb][ks], acc[rb][cb], 0, 0, 0);
            }
        }
    }

    // epilogue: D col = lane&15, row = (lane>>4)*4 + reg; scale by dinv, store f16
#pragma unroll
    for (int rb = 0; rb < 4; ++rb) {
#pragma unroll
        for (int r = 0; r < 4; ++r) {
            const int grow = row0 + rg * 64 + rb * 16 + lg * 4 + r;
            if (grow < N) {
                const float d = dinv[grow];
#pragma unroll
                for (int cb = 0; cb < 2; ++cb)
                    H[(size_t)grow * HID + cg * 32 + cb * 16 + li] = (f16)(acc[rb][cb][r] * d);
            }
        }
    }
}

// ================= aggregation (row-gather, f16 h', unroll 8) =================
// One wave per node; lane owns 2 cols via one uint load.
// F16OUT: write f16 activation (layers 0,1); else f32 final (layer 2).

template<bool F16OUT>
__global__ __launch_bounds__(256) void k_agg_csr(const f16* __restrict__ h,
                                                 const int* __restrict__ csr_src,
                                                 const int* __restrict__ row_ptr,
                                                 const float* __restrict__ dinv,
                                                 const float* __restrict__ bias,
                                                 void* __restrict__ outv, int N) {
    int node = (blockIdx.x * 256 + threadIdx.x) >> 6;
    if (node >= N) return;
    int lane = threadIdx.x & 63;
    const unsigned int* h32 = reinterpret_cast<const unsigned int*>(h);  // row = 64 uints

    float2 self = h2f(h32[(size_t)node * 64 + lane]);
    float accx = self.x, accy = self.y;

    int j = row_ptr[node];
    const int end = row_ptr[node + 1];

    for (; j + 8 <= end; j += 8) {
        int s0 = csr_src[j];
        int s1 = csr_src[j + 1];
        int s2 = csr_src[j + 2];
        int s3 = csr_src[j + 3];
        int s4 = csr_src[j + 4];
        int s5 = csr_src[j + 5];
        int s6 = csr_src[j + 6];
        int s7 = csr_src[j + 7];
        unsigned int u0 = h32[(size_t)s0 * 64 + lane];
        unsigned int u1 = h32[(size_t)s1 * 64 + lane];
        unsigned int u2 = h32[(size_t)s2 * 64 + lane];
        unsigned int u3 = h32[(size_t)s3 * 64 + lane];
        unsigned int u4 = h32[(size_t)s4 * 64 + lane];
        unsigned int u5 = h32[(size_t)s5 * 64 + lane];
        unsigned int u6 = h32[(size_t)s6 * 64 + lane];
        unsigned int u7 = h32[(size_t)s7 * 64 + lane];
        float2 v0 = h2f(u0), v1 = h2f(u1), v2 = h2f(u2), v3 = h2f(u3);
        float2 v4 = h2f(u4), v5 = h2f(u5), v6 = h2f(u6), v7 = h2f(u7);
        accx += ((v0.x + v1.x) + (v2.x + v3.x)) + ((v4.x + v5.x) + (v6.x + v7.x));
        accy += ((v0.y + v1.y) + (v2.y + v3.y)) + ((v4.y + v5.y) + (v6.y + v7.y));
    }
    for (; j < end; ++j) {
        float2 v = h2f(h32[(size_t)csr_src[j] * 64 + lane]);
        accx += v.x;
        accy += v.y;
    }

    float di = dinv[node];
    int c = lane * 2;
    float ox = fmaf(di, accx, bias[c]);
    float oy = fmaf(di, accy, bias[c + 1]);
    if constexpr (F16OUT) {
        f16x2 o = {(f16)ox, (f16)oy};
        *reinterpret_cast<f16x2*>((f16*)outv + (size_t)node * HID + c) = o;
    } else {
        *reinterpret_cast<float2*>((float*)outv + (size_t)node * HID + c) = make_float2(ox, oy);
    }
}

// ================= launch =================

extern "C" void kernel_launch(void* const* d_in, const int* in_sizes, int n_in,
                              void* d_out, int out_size, void* d_ws, size_t ws_size,
                              hipStream_t stream) {
    const float* x  = (const float*)d_in[0];
    const int*   ei = (const int*)  d_in[1];
    const float* W0 = (const float*)d_in[2];
    const float* b0 = (const float*)d_in[3];
    const float* W1 = (const float*)d_in[4];
    const float* b1 = (const float*)d_in[5];
    const float* W2 = (const float*)d_in[6];
    const float* b2 = (const float*)d_in[7];

    const int N = in_sizes[0] / HID;
    const int E = in_sizes[1] / 2;
    const int* row = ei;        // sources
    const int* col = ei + E;    // destinations

    const int nb_n = (N + 255) / 256;

    // workspace layout
    f16*   h16     = (f16*)d_ws;                      // [N,128] f16 (= h', dinv-scaled)
    float* dinv    = (float*)(h16 + (size_t)N * HID); // [N]
    int*   cnt     = (int*)(dinv + N);                // [N]
    int*   row_ptr = cnt + N;                         // [N+1]
    int*   fill    = row_ptr + (N + 1);               // [N]
    int*   bsum    = fill + N;                        // [nb_n]
    int*   csr_src = bsum + nb_n;                     // [E]
    f16*   wt0     = (f16*)(csr_src + E);             // [32768] each
    f16*   wt1     = wt0 + 32768;
    f16*   wt2     = wt1 + 32768;
    f16*   act     = (f16*)d_out;                     // layers 0,1 activation (f16 in d_out)
    float* out     = (float*)d_out;                   // final f32 output

    const int nb_e    = (E + 255) / 256;
    const int nb_gemm = (N + BR - 1) / BR;
    const int nb_agg  = (N * 64 + 255) / 256;
    const int nb_fill = ((E + FILL_CHUNK - 1) / FILL_CHUNK) * 8;

    // ---- CSR build + W prep ----
    hipMemsetAsync(cnt, 0, (size_t)N * sizeof(int), stream);
    k_wprep<<<16, 256, 0, stream>>>(W0, wt0);
    k_wprep<<<16, 256, 0, stream>>>(W1, wt1);
    k_wprep<<<16, 256, 0, stream>>>(W2, wt2);
    k_deg_count <<<nb_e, 256, 0, stream>>>(col, cnt, E);
    k_scan_block<<<nb_n, 256, 0, stream>>>(cnt, row_ptr, bsum, dinv, N);
    k_scan_bsum <<<1, 1024, 0, stream>>>(bsum, nb_n);
    k_scan_add  <<<nb_n, 256, 0, stream>>>(row_ptr, bsum, fill, N, E);
    k_fill      <<<nb_fill, 256, 0, stream>>>(row, col, fill, csr_src, E, N);

    // ---- layer 0: x (f32) -> h16 -> act (f16) ----
    k_gemm<0>      <<<nb_gemm, 512, 0, stream>>>(x, wt0, dinv, h16, N);
    k_agg_csr<true><<<nb_agg, 256, 0, stream>>>(h16, csr_src, row_ptr, dinv, b0, act, N);
    // ---- layer 1: act (f16) -> h16 -> act (f16) ----
    k_gemm<1>      <<<nb_gemm, 512, 0, stream>>>(act, wt1, dinv, h16, N);
    k_agg_csr<true><<<nb_agg, 256, 0, stream>>>(h16, csr_src, row_ptr, dinv, b1, act, N);
    // ---- layer 2: act (f16) -> h16 -> out (f32) ----
    k_gemm<1>      <<<nb_gemm, 512, 0, stream>>>(act, wt2, dinv, h16, N);
    k_agg_csr<false><<<nb_agg, 256, 0, stream>>>(h16, csr_src, row_ptr, dinv, b2, out, N);
}

// Round 10
// 450.717 us; speedup vs baseline: 2.0873x; 1.0107x over previous
//
#include <hip/hip_runtime.h>

#define HID 128
#define BR  128        // GEMM rows per block
#define FILL_CHUNK 2048

typedef _Float16 f16;
typedef f16 f16x2 __attribute__((ext_vector_type(2)));
typedef f16 f16x4 __attribute__((ext_vector_type(4)));
typedef f16 f16x8 __attribute__((ext_vector_type(8)));
typedef float f32x4 __attribute__((ext_vector_type(4)));

static __device__ __forceinline__ float2 h2f(unsigned int u) {
    f16x2 v;
    __builtin_memcpy(&v, &u, 4);
    return make_float2((float)v[0], (float)v[1]);
}

// ================= degree / CSR build =================

// XCD-range-filtered count: block b -> edge chunk (b>>3), col-range (b&7)
__global__ void k_deg_count(const int* __restrict__ col, int* __restrict__ cnt, int E, int N) {
    const int xcd = blockIdx.x & 7;
    const int chunk = blockIdx.x >> 3;
    const int per = (N + 7) >> 3;
    const int lo = xcd * per;
    const int hi = min(N, lo + per);
    const int eend = min(E, (chunk + 1) * FILL_CHUNK);
    for (int e = chunk * FILL_CHUNK + threadIdx.x; e < eend; e += 256) {
        int c = col[e];
        if (c >= lo && c < hi) atomicAdd(&cnt[c], 1);
    }
}

__global__ void k_scan_block(const int* __restrict__ cnt, int* __restrict__ excl,
                             int* __restrict__ bsum, float* __restrict__ dinv, int N) {
    __shared__ int s[256];
    int i = blockIdx.x * 256 + threadIdx.x;
    int v = (i < N) ? cnt[i] : 0;
    if (i < N) dinv[i] = 1.0f / sqrtf((float)(v + 1));   // +1 = self-loop
    s[threadIdx.x] = v;
    __syncthreads();
    for (int off = 1; off < 256; off <<= 1) {
        int t = (threadIdx.x >= off) ? s[threadIdx.x - off] : 0;
        __syncthreads();
        s[threadIdx.x] += t;
        __syncthreads();
    }
    if (i < N) excl[i] = s[threadIdx.x] - v;
    if (threadIdx.x == 255) bsum[blockIdx.x] = s[255];
}

__global__ __launch_bounds__(1024) void k_scan_bsum(int* __restrict__ bsum, int nb) {
    __shared__ int s[1024];
    int i = threadIdx.x;
    int v = (i < nb) ? bsum[i] : 0;
    s[i] = v;
    __syncthreads();
    for (int off = 1; off < 1024; off <<= 1) {
        int t = (i >= off) ? s[i - off] : 0;
        __syncthreads();
        s[i] += t;
        __syncthreads();
    }
    if (i < nb) bsum[i] = s[i] - v;
}

__global__ void k_scan_add(int* __restrict__ row_ptr, const int* __restrict__ bsum,
                           int* __restrict__ fill, int N, int E) {
    int i = blockIdx.x * 256 + threadIdx.x;
    if (i < N) {
        int v = row_ptr[i] + bsum[blockIdx.x];
        row_ptr[i] = v;
        fill[i] = v;
    }
    if (i == 0) row_ptr[N] = E;
}

// XCD-range-filtered scatter
__global__ void k_fill(const int* __restrict__ row, const int* __restrict__ col,
                       int* __restrict__ fill, int* __restrict__ csr_src, int E, int N) {
    const int xcd = blockIdx.x & 7;
    const int chunk = blockIdx.x >> 3;
    const int per = (N + 7) >> 3;
    const int lo = xcd * per;
    const int hi = min(N, lo + per);
    const int eend = min(E, (chunk + 1) * FILL_CHUNK);
    for (int e = chunk * FILL_CHUNK + threadIdx.x; e < eend; e += 256) {
        int c = col[e];
        if (c >= lo && c < hi) {
            int p = atomicAdd(&fill[c], 1);
            csr_src[p] = row[e];
        }
    }
}

// ================= W prep (all 3 layers, one launch) =================
// element (k,n) -> (k>>3)*1024 + n*8 + (k&7); hi [0,16384), lo [16384,32768)

__global__ void k_wprep3(const float* __restrict__ W0, const float* __restrict__ W1,
                         const float* __restrict__ W2, f16* __restrict__ out) {
    const int b = blockIdx.x;              // 48 blocks
    const int which = b >> 4;
    const float* W = which == 0 ? W0 : (which == 1 ? W1 : W2);
    f16* o = out + which * 32768;
    int i = (b & 15) * 256 + threadIdx.x;  // 4096 float4s
    int k = i >> 5, n0 = (i & 31) * 4;
    float4 v = reinterpret_cast<const float4*>(W)[i];
    float vv[4] = {v.x, v.y, v.z, v.w};
#pragma unroll
    for (int e = 0; e < 4; ++e) {
        int n = n0 + e;
        int idx = (k >> 3) * 1024 + n * 8 + (k & 7);
        f16 h = (f16)vv[e];
        o[idx] = h;
        o[16384 + idx] = (f16)(vv[e] - (float)h);
    }
}

// ================= GEMM: H16 = f16( dinv .* (act(X) @ W) ) =================
// Swapped-operand MFMA: D = mfma(A=W^T-frag, B=X-frag) so D's reg axis runs
// along features -> f16x4 (8 B) epilogue stores instead of 32x 2 B.
// Wave w: n-group ng=w&3 (2 n-blocks), m-group mg=w>>2 (4 m-blocks).
// MODE 0: f32 input, no relu, 3 limbs (Wh*Xh + Wl*Xh + Wh*Xl), 64 KB LDS.
// MODE 1: f16 input (exact), relu, 2 limbs (Wh*X + Wl*X), 32 KB LDS.

template<int MODE>
__global__ __launch_bounds__(512, 4) void k_gemm(const void* __restrict__ Xv,
                                                 const f16* __restrict__ Wt,
                                                 const float* __restrict__ dinv,
                                                 f16* __restrict__ H, int N) {
    __shared__ f16 Xs[MODE == 0 ? 2 * 16384 : 16384];
    const int t = threadIdx.x;
    const int row0 = blockIdx.x * BR;

    const int w  = t >> 6;
    const int l  = t & 63;
    const int lg = l >> 4;
    const int li = l & 15;
    const int ng = w & 3;           // 0..3 -> n-blocks ng*2, ng*2+1
    const int mg = w >> 2;          // 0..1 -> m-blocks mg*4 .. +3

    // W fragments (A operand), issued before X staging (latency hidden)
    f16x8 Wh[2][4], Wl[2][4];
#pragma unroll
    for (int nb = 0; nb < 2; ++nb) {
        const int ncol = (ng * 2 + nb) * 16 + li;
#pragma unroll
        for (int ks = 0; ks < 4; ++ks) {
            const int idx = (ks * 4 + lg) * 1024 + ncol * 8;
            Wh[nb][ks] = *reinterpret_cast<const f16x8*>(&Wt[idx]);
            Wl[nb][ks] = *reinterpret_cast<const f16x8*>(&Wt[16384 + idx]);
        }
    }

    if constexpr (MODE == 0) {
        // f32 input: hi/lo split, 16B-chunk swizzle
        const float* X = (const float*)Xv;
        for (int i = t; i < 4096; i += 512) {
            int r = i >> 5, q = i & 31;
            int gr = row0 + r;
            float4 v = make_float4(0.f, 0.f, 0.f, 0.f);
            if (gr < N) v = reinterpret_cast<const float4*>(X + (size_t)gr * HID)[q];
            f16 h0 = (f16)v.x, h1 = (f16)v.y, h2 = (f16)v.z, h3 = (f16)v.w;
            f16 l0 = (f16)(v.x - (float)h0), l1 = (f16)(v.y - (float)h1);
            f16 l2 = (f16)(v.z - (float)h2), l3 = (f16)(v.w - (float)h3);
            int base = r * 128 + (((q >> 1) ^ (r & 7)) * 8) + (q & 1) * 4;
            *reinterpret_cast<f16x4*>(&Xs[base])         = (f16x4){h0, h1, h2, h3};
            *reinterpret_cast<f16x4*>(&Xs[16384 + base]) = (f16x4){l0, l1, l2, l3};
        }
    } else {
        // f16 input: relu, straight copy, 16B-chunk swizzle (2048 chunks)
        const f16* X = (const f16*)Xv;
        for (int i = t; i < 2048; i += 512) {
            int r = i >> 4, q = i & 15;
            int gr = row0 + r;
            f16x8 v = {};
            if (gr < N) v = *reinterpret_cast<const f16x8*>(X + (size_t)gr * HID + q * 8);
#pragma unroll
            for (int e = 0; e < 8; ++e) v[e] = v[e] > (f16)0 ? v[e] : (f16)0;
            *reinterpret_cast<f16x8*>(&Xs[r * 128 + ((q ^ (r & 7)) * 8)]) = v;
        }
    }
    __syncthreads();

    f32x4 acc[2][4];
#pragma unroll
    for (int nb = 0; nb < 2; ++nb)
#pragma unroll
        for (int mb = 0; mb < 4; ++mb) acc[nb][mb] = (f32x4){0.f, 0.f, 0.f, 0.f};

#pragma unroll
    for (int mb = 0; mb < 4; ++mb) {
        const int arow = mg * 64 + mb * 16 + li;
#pragma unroll
        for (int ks = 0; ks < 4; ++ks) {
            const int idx = arow * 128 + (((ks * 4 + lg) ^ (arow & 7)) * 8);
            f16x8 Xh = *reinterpret_cast<const f16x8*>(&Xs[idx]);
#pragma unroll
            for (int nb = 0; nb < 2; ++nb) {
                acc[nb][mb] = __builtin_amdgcn_mfma_f32_16x16x32_f16(Wh[nb][ks], Xh, acc[nb][mb], 0, 0, 0);
                acc[nb][mb] = __builtin_amdgcn_mfma_f32_16x16x32_f16(Wl[nb][ks], Xh, acc[nb][mb], 0, 0, 0);
            }
            if constexpr (MODE == 0) {
                f16x8 Xl = *reinterpret_cast<const f16x8*>(&Xs[16384 + idx]);
#pragma unroll
                for (int nb = 0; nb < 2; ++nb)
                    acc[nb][mb] = __builtin_amdgcn_mfma_f32_16x16x32_f16(Wh[nb][ks], Xl, acc[nb][mb], 0, 0, 0);
            }
        }
    }

    // epilogue: D col(lane&15) = m-offset, row(lg*4+reg) = n-offset -> f16x4 stores
#pragma unroll
    for (int mb = 0; mb < 4; ++mb) {
        const int m = row0 + mg * 64 + mb * 16 + li;
        if (m < N) {
            const float d = dinv[m];
#pragma unroll
            for (int nb = 0; nb < 2; ++nb) {
                f16x4 o = {(f16)(acc[nb][mb][0] * d), (f16)(acc[nb][mb][1] * d),
                           (f16)(acc[nb][mb][2] * d), (f16)(acc[nb][mb][3] * d)};
                *reinterpret_cast<f16x4*>(&H[(size_t)m * HID + (ng * 2 + nb) * 16 + lg * 4]) = o;
            }
        }
    }
}

// ================= aggregation (row-gather, f16 h', unroll 8) =================

template<bool F16OUT>
__global__ __launch_bounds__(256) void k_agg_csr(const f16* __restrict__ h,
                                                 const int* __restrict__ csr_src,
                                                 const int* __restrict__ row_ptr,
                                                 const float* __restrict__ dinv,
                                                 const float* __restrict__ bias,
                                                 void* __restrict__ outv, int N) {
    int node = (blockIdx.x * 256 + threadIdx.x) >> 6;
    if (node >= N) return;
    int lane = threadIdx.x & 63;
    const unsigned int* h32 = reinterpret_cast<const unsigned int*>(h);  // row = 64 uints

    float2 self = h2f(h32[(size_t)node * 64 + lane]);
    float accx = self.x, accy = self.y;

    int j = row_ptr[node];
    const int end = row_ptr[node + 1];

    for (; j + 8 <= end; j += 8) {
        int s0 = csr_src[j];
        int s1 = csr_src[j + 1];
        int s2 = csr_src[j + 2];
        int s3 = csr_src[j + 3];
        int s4 = csr_src[j + 4];
        int s5 = csr_src[j + 5];
        int s6 = csr_src[j + 6];
        int s7 = csr_src[j + 7];
        unsigned int u0 = h32[(size_t)s0 * 64 + lane];
        unsigned int u1 = h32[(size_t)s1 * 64 + lane];
        unsigned int u2 = h32[(size_t)s2 * 64 + lane];
        unsigned int u3 = h32[(size_t)s3 * 64 + lane];
        unsigned int u4 = h32[(size_t)s4 * 64 + lane];
        unsigned int u5 = h32[(size_t)s5 * 64 + lane];
        unsigned int u6 = h32[(size_t)s6 * 64 + lane];
        unsigned int u7 = h32[(size_t)s7 * 64 + lane];
        float2 v0 = h2f(u0), v1 = h2f(u1), v2 = h2f(u2), v3 = h2f(u3);
        float2 v4 = h2f(u4), v5 = h2f(u5), v6 = h2f(u6), v7 = h2f(u7);
        accx += ((v0.x + v1.x) + (v2.x + v3.x)) + ((v4.x + v5.x) + (v6.x + v7.x));
        accy += ((v0.y + v1.y) + (v2.y + v3.y)) + ((v4.y + v5.y) + (v6.y + v7.y));
    }
    for (; j < end; ++j) {
        float2 v = h2f(h32[(size_t)csr_src[j] * 64 + lane]);
        accx += v.x;
        accy += v.y;
    }

    float di = dinv[node];
    int c = lane * 2;
    float ox = fmaf(di, accx, bias[c]);
    float oy = fmaf(di, accy, bias[c + 1]);
    if constexpr (F16OUT) {
        f16x2 o = {(f16)ox, (f16)oy};
        *reinterpret_cast<f16x2*>((f16*)outv + (size_t)node * HID + c) = o;
    } else {
        *reinterpret_cast<float2*>((float*)outv + (size_t)node * HID + c) = make_float2(ox, oy);
    }
}

// ================= launch =================

extern "C" void kernel_launch(void* const* d_in, const int* in_sizes, int n_in,
                              void* d_out, int out_size, void* d_ws, size_t ws_size,
                              hipStream_t stream) {
    const float* x  = (const float*)d_in[0];
    const int*   ei = (const int*)  d_in[1];
    const float* W0 = (const float*)d_in[2];
    const float* b0 = (const float*)d_in[3];
    const float* W1 = (const float*)d_in[4];
    const float* b1 = (const float*)d_in[5];
    const float* W2 = (const float*)d_in[6];
    const float* b2 = (const float*)d_in[7];

    const int N = in_sizes[0] / HID;
    const int E = in_sizes[1] / 2;
    const int* row = ei;        // sources
    const int* col = ei + E;    // destinations

    const int nb_n = (N + 255) / 256;

    // workspace layout
    f16*   h16     = (f16*)d_ws;                      // [N,128] f16 (= h', dinv-scaled)
    float* dinv    = (float*)(h16 + (size_t)N * HID); // [N]
    int*   cnt     = (int*)(dinv + N);                // [N]
    int*   row_ptr = cnt + N;                         // [N+1]
    int*   fill    = row_ptr + (N + 1);               // [N]
    int*   bsum    = fill + N;                        // [nb_n]
    int*   csr_src = bsum + nb_n;                     // [E]
    f16*   wt      = (f16*)(csr_src + E);             // [3*32768]
    f16*   wt0     = wt;
    f16*   wt1     = wt + 32768;
    f16*   wt2     = wt + 65536;
    f16*   act     = (f16*)d_out;                     // layers 0,1 activation (f16 in d_out)
    float* out     = (float*)d_out;                   // final f32 output

    const int nb_gemm = (N + BR - 1) / BR;
    const int nb_agg  = (N * 64 + 255) / 256;
    const int nb_fill = ((E + FILL_CHUNK - 1) / FILL_CHUNK) * 8;

    // ---- CSR build + W prep ----
    hipMemsetAsync(cnt, 0, (size_t)N * sizeof(int), stream);
    k_wprep3<<<48, 256, 0, stream>>>(W0, W1, W2, wt);
    k_deg_count <<<nb_fill, 256, 0, stream>>>(col, cnt, E, N);
    k_scan_block<<<nb_n, 256, 0, stream>>>(cnt, row_ptr, bsum, dinv, N);
    k_scan_bsum <<<1, 1024, 0, stream>>>(bsum, nb_n);
    k_scan_add  <<<nb_n, 256, 0, stream>>>(row_ptr, bsum, fill, N, E);
    k_fill      <<<nb_fill, 256, 0, stream>>>(row, col, fill, csr_src, E, N);

    // ---- layer 0: x (f32) -> h16 -> act (f16) ----
    k_gemm<0>      <<<nb_gemm, 512, 0, stream>>>(x, wt0, dinv, h16, N);
    k_agg_csr<true><<<nb_agg, 256, 0, stream>>>(h16, csr_src, row_ptr, dinv, b0, act, N);
    // ---- layer 1: act (f16) -> h16 -> act (f16) ----
    k_gemm<1>      <<<nb_gemm, 512, 0, stream>>>(act, wt1, dinv, h16, N);
    k_agg_csr<true><<<nb_agg, 256, 0, stream>>>(h16, csr_src, row_ptr, dinv, b1, act, N);
    // ---- layer 2: act (f16) -> h16 -> out (f32) ----
    k_gemm<1>      <<<nb_gemm, 512, 0, stream>>>(act, wt2, dinv, h16, N);
    k_agg_csr<false><<<nb_agg, 256, 0, stream>>>(h16, csr_src, row_ptr, dinv, b2, out, N);
}

// Round 11
// 424.216 us; speedup vs baseline: 2.2176x; 1.0625x over previous
//
#include <hip/hip_runtime.h>

#define HID 128
#define BR  128        // GEMM rows per block
#define FILL_CHUNK 2048

typedef _Float16 f16;
typedef f16 f16x2 __attribute__((ext_vector_type(2)));
typedef f16 f16x4 __attribute__((ext_vector_type(4)));
typedef f16 f16x8 __attribute__((ext_vector_type(8)));
typedef float f32x4 __attribute__((ext_vector_type(4)));

static __device__ __forceinline__ float2 h2f(unsigned int u) {
    f16x2 v;
    __builtin_memcpy(&v, &u, 4);
    return make_float2((float)v[0], (float)v[1]);
}

// ================= degree / CSR build =================

// XCD-range-filtered count: block b -> edge chunk (b>>3), col-range (b&7)
__global__ void k_deg_count(const int* __restrict__ col, int* __restrict__ cnt, int E, int N) {
    const int xcd = blockIdx.x & 7;
    const int chunk = blockIdx.x >> 3;
    const int per = (N + 7) >> 3;
    const int lo = xcd * per;
    const int hi = min(N, lo + per);
    const int eend = min(E, (chunk + 1) * FILL_CHUNK);
    for (int e = chunk * FILL_CHUNK + threadIdx.x; e < eend; e += 256) {
        int c = col[e];
        if (c >= lo && c < hi) atomicAdd(&cnt[c], 1);
    }
}

__global__ void k_scan_block(const int* __restrict__ cnt, int* __restrict__ excl,
                             int* __restrict__ bsum, float* __restrict__ dinv, int N) {
    __shared__ int s[256];
    int i = blockIdx.x * 256 + threadIdx.x;
    int v = (i < N) ? cnt[i] : 0;
    if (i < N) dinv[i] = 1.0f / sqrtf((float)(v + 1));   // +1 = self-loop
    s[threadIdx.x] = v;
    __syncthreads();
    for (int off = 1; off < 256; off <<= 1) {
        int t = (threadIdx.x >= off) ? s[threadIdx.x - off] : 0;
        __syncthreads();
        s[threadIdx.x] += t;
        __syncthreads();
    }
    if (i < N) excl[i] = s[threadIdx.x] - v;
    if (threadIdx.x == 255) bsum[blockIdx.x] = s[255];
}

__global__ __launch_bounds__(1024) void k_scan_bsum(int* __restrict__ bsum, int nb) {
    __shared__ int s[1024];
    int i = threadIdx.x;
    int v = (i < nb) ? bsum[i] : 0;
    s[i] = v;
    __syncthreads();
    for (int off = 1; off < 1024; off <<= 1) {
        int t = (i >= off) ? s[i - off] : 0;
        __syncthreads();
        s[i] += t;
        __syncthreads();
    }
    if (i < nb) bsum[i] = s[i] - v;
}

__global__ void k_scan_add(int* __restrict__ row_ptr, const int* __restrict__ bsum,
                           int* __restrict__ fill, int N, int E) {
    int i = blockIdx.x * 256 + threadIdx.x;
    if (i < N) {
        int v = row_ptr[i] + bsum[blockIdx.x];
        row_ptr[i] = v;
        fill[i] = v;
    }
    if (i == 0) row_ptr[N] = E;
}

// XCD-range-filtered scatter
__global__ void k_fill(const int* __restrict__ row, const int* __restrict__ col,
                       int* __restrict__ fill, int* __restrict__ csr_src, int E, int N) {
    const int xcd = blockIdx.x & 7;
    const int chunk = blockIdx.x >> 3;
    const int per = (N + 7) >> 3;
    const int lo = xcd * per;
    const int hi = min(N, lo + per);
    const int eend = min(E, (chunk + 1) * FILL_CHUNK);
    for (int e = chunk * FILL_CHUNK + threadIdx.x; e < eend; e += 256) {
        int c = col[e];
        if (c >= lo && c < hi) {
            int p = atomicAdd(&fill[c], 1);
            csr_src[p] = row[e];
        }
    }
}

// ================= W prep (all 3 layers, one launch) =================
// element (k,n) -> (k>>3)*1024 + n*8 + (k&7); hi [0,16384), lo [16384,32768)

__global__ void k_wprep3(const float* __restrict__ W0, const float* __restrict__ W1,
                         const float* __restrict__ W2, f16* __restrict__ out) {
    const int b = blockIdx.x;              // 48 blocks
    const int which = b >> 4;
    const float* W = which == 0 ? W0 : (which == 1 ? W1 : W2);
    f16* o = out + which * 32768;
    int i = (b & 15) * 256 + threadIdx.x;  // 4096 float4s
    int k = i >> 5, n0 = (i & 31) * 4;
    float4 v = reinterpret_cast<const float4*>(W)[i];
    float vv[4] = {v.x, v.y, v.z, v.w};
#pragma unroll
    for (int e = 0; e < 4; ++e) {
        int n = n0 + e;
        int idx = (k >> 3) * 1024 + n * 8 + (k & 7);
        f16 h = (f16)vv[e];
        o[idx] = h;
        o[16384 + idx] = (f16)(vv[e] - (float)h);
    }
}

// ================= GEMM: H16 = f16( dinv .* (X @ W) ) =================
// Swapped-operand MFMA: D = mfma(A=W^T-frag, B=X-frag); f16x4 epilogue stores.
// MODE 0: f32 input, 3 limbs (Wh*Xh + Wl*Xh + Wh*Xl), 64 KB LDS, swizzle at stage.
// MODE 1: f16 input PRE-SWIZZLED + PRE-RELU'd by agg -> staging is a pure
//         linear 32 KB copy (content already in swizzled layout).

template<int MODE>
__global__ __launch_bounds__(512, 4) void k_gemm(const void* __restrict__ Xv,
                                                 const f16* __restrict__ Wt,
                                                 const float* __restrict__ dinv,
                                                 f16* __restrict__ H, int N) {
    __shared__ f16 Xs[MODE == 0 ? 2 * 16384 : 16384];
    const int t = threadIdx.x;
    const int row0 = blockIdx.x * BR;

    const int w  = t >> 6;
    const int l  = t & 63;
    const int lg = l >> 4;
    const int li = l & 15;
    const int ng = w & 3;           // 0..3 -> n-blocks ng*2, ng*2+1
    const int mg = w >> 2;          // 0..1 -> m-blocks mg*4 .. +3

    // W fragments (A operand), issued before X staging (latency hidden)
    f16x8 Wh[2][4], Wl[2][4];
#pragma unroll
    for (int nb = 0; nb < 2; ++nb) {
        const int ncol = (ng * 2 + nb) * 16 + li;
#pragma unroll
        for (int ks = 0; ks < 4; ++ks) {
            const int idx = (ks * 4 + lg) * 1024 + ncol * 8;
            Wh[nb][ks] = *reinterpret_cast<const f16x8*>(&Wt[idx]);
            Wl[nb][ks] = *reinterpret_cast<const f16x8*>(&Wt[16384 + idx]);
        }
    }

    if constexpr (MODE == 0) {
        // f32 input: hi/lo split, 16B-chunk swizzle
        const float* X = (const float*)Xv;
        for (int i = t; i < 4096; i += 512) {
            int r = i >> 5, q = i & 31;
            int gr = row0 + r;
            float4 v = make_float4(0.f, 0.f, 0.f, 0.f);
            if (gr < N) v = reinterpret_cast<const float4*>(X + (size_t)gr * HID)[q];
            f16 h0 = (f16)v.x, h1 = (f16)v.y, h2 = (f16)v.z, h3 = (f16)v.w;
            f16 l0 = (f16)(v.x - (float)h0), l1 = (f16)(v.y - (float)h1);
            f16 l2 = (f16)(v.z - (float)h2), l3 = (f16)(v.w - (float)h3);
            int base = r * 128 + (((q >> 1) ^ (r & 7)) * 8) + (q & 1) * 4;
            *reinterpret_cast<f16x4*>(&Xs[base])         = (f16x4){h0, h1, h2, h3};
            *reinterpret_cast<f16x4*>(&Xs[16384 + base]) = (f16x4){l0, l1, l2, l3};
        }
    } else {
        // f16 input already relu'd + swizzled: straight 32 KB copy (16 B/thread x 4).
        // Rows >= N read garbage (within d_out allocation) -> poisons only D cols >= N (not stored).
        const f16* src = (const f16*)Xv + (size_t)row0 * HID;
        for (int i = t; i < 2048; i += 512)
            *reinterpret_cast<f16x8*>(&Xs[i * 8]) = *reinterpret_cast<const f16x8*>(src + (size_t)i * 8);
    }
    __syncthreads();

    f32x4 acc[2][4];
#pragma unroll
    for (int nb = 0; nb < 2; ++nb)
#pragma unroll
        for (int mb = 0; mb < 4; ++mb) acc[nb][mb] = (f32x4){0.f, 0.f, 0.f, 0.f};

#pragma unroll
    for (int mb = 0; mb < 4; ++mb) {
        const int arow = mg * 64 + mb * 16 + li;
#pragma unroll
        for (int ks = 0; ks < 4; ++ks) {
            const int idx = arow * 128 + (((ks * 4 + lg) ^ (arow & 7)) * 8);
            f16x8 Xh = *reinterpret_cast<const f16x8*>(&Xs[idx]);
#pragma unroll
            for (int nb = 0; nb < 2; ++nb) {
                acc[nb][mb] = __builtin_amdgcn_mfma_f32_16x16x32_f16(Wh[nb][ks], Xh, acc[nb][mb], 0, 0, 0);
                acc[nb][mb] = __builtin_amdgcn_mfma_f32_16x16x32_f16(Wl[nb][ks], Xh, acc[nb][mb], 0, 0, 0);
            }
            if constexpr (MODE == 0) {
                f16x8 Xl = *reinterpret_cast<const f16x8*>(&Xs[16384 + idx]);
#pragma unroll
                for (int nb = 0; nb < 2; ++nb)
                    acc[nb][mb] = __builtin_amdgcn_mfma_f32_16x16x32_f16(Wh[nb][ks], Xl, acc[nb][mb], 0, 0, 0);
            }
        }
    }

    // epilogue: D col(lane&15) = m-offset, row(lg*4+reg) = n-offset -> f16x4 stores
#pragma unroll
    for (int mb = 0; mb < 4; ++mb) {
        const int m = row0 + mg * 64 + mb * 16 + li;
        if (m < N) {
            const float d = dinv[m];
#pragma unroll
            for (int nb = 0; nb < 2; ++nb) {
                f16x4 o = {(f16)(acc[nb][mb][0] * d), (f16)(acc[nb][mb][1] * d),
                           (f16)(acc[nb][mb][2] * d), (f16)(acc[nb][mb][3] * d)};
                *reinterpret_cast<f16x4*>(&H[(size_t)m * HID + (ng * 2 + nb) * 16 + lg * 4]) = o;
            }
        }
    }
}

// ================= aggregation (row-gather, 2 nodes/wave, unroll 8) =================
// 32 lanes per node; lane owns uint2 (4 cols) -> 2x independent gather chains per
// wave vs 1-node/wave. F16OUT: store relu'd, LDS-swizzled f16 activation (consumed
// by gemm<1> as a linear copy); else plain f32 final output.

template<bool F16OUT>
__global__ __launch_bounds__(256) void k_agg_csr(const f16* __restrict__ h,
                                                 const int* __restrict__ csr_src,
                                                 const int* __restrict__ row_ptr,
                                                 const float* __restrict__ dinv,
                                                 const float* __restrict__ bias,
                                                 void* __restrict__ outv, int N) {
    const int node = blockIdx.x * 8 + (threadIdx.x >> 5);
    if (node >= N) return;
    const int l = threadIdx.x & 31;
    const uint2* h2 = reinterpret_cast<const uint2*>(h);   // row = 32 uint2

    uint2 us = h2[(size_t)node * 32 + l];
    float2 a0 = h2f(us.x), a1 = h2f(us.y);
    float acc0 = a0.x, acc1 = a0.y, acc2 = a1.x, acc3 = a1.y;

    int j = row_ptr[node];
    const int end = row_ptr[node + 1];

    for (; j + 8 <= end; j += 8) {
        int s0 = csr_src[j];
        int s1 = csr_src[j + 1];
        int s2 = csr_src[j + 2];
        int s3 = csr_src[j + 3];
        int s4 = csr_src[j + 4];
        int s5 = csr_src[j + 5];
        int s6 = csr_src[j + 6];
        int s7 = csr_src[j + 7];
        uint2 u0 = h2[(size_t)s0 * 32 + l];
        uint2 u1 = h2[(size_t)s1 * 32 + l];
        uint2 u2 = h2[(size_t)s2 * 32 + l];
        uint2 u3 = h2[(size_t)s3 * 32 + l];
        uint2 u4 = h2[(size_t)s4 * 32 + l];
        uint2 u5 = h2[(size_t)s5 * 32 + l];
        uint2 u6 = h2[(size_t)s6 * 32 + l];
        uint2 u7 = h2[(size_t)s7 * 32 + l];
        float2 v0 = h2f(u0.x), w0 = h2f(u0.y), v1 = h2f(u1.x), w1 = h2f(u1.y);
        float2 v2 = h2f(u2.x), w2 = h2f(u2.y), v3 = h2f(u3.x), w3 = h2f(u3.y);
        float2 v4 = h2f(u4.x), w4 = h2f(u4.y), v5 = h2f(u5.x), w5 = h2f(u5.y);
        float2 v6 = h2f(u6.x), w6 = h2f(u6.y), v7 = h2f(u7.x), w7 = h2f(u7.y);
        acc0 += ((v0.x + v1.x) + (v2.x + v3.x)) + ((v4.x + v5.x) + (v6.x + v7.x));
        acc1 += ((v0.y + v1.y) + (v2.y + v3.y)) + ((v4.y + v5.y) + (v6.y + v7.y));
        acc2 += ((w0.x + w1.x) + (w2.x + w3.x)) + ((w4.x + w5.x) + (w6.x + w7.x));
        acc3 += ((w0.y + w1.y) + (w2.y + w3.y)) + ((w4.y + w5.y) + (w6.y + w7.y));
    }
    for (; j < end; ++j) {
        uint2 u = h2[(size_t)csr_src[j] * 32 + l];
        float2 v = h2f(u.x), w = h2f(u.y);
        acc0 += v.x; acc1 += v.y; acc2 += w.x; acc3 += w.y;
    }

    const float di = dinv[node];
    const float4 bv = reinterpret_cast<const float4*>(bias)[l];
    float o0 = fmaf(di, acc0, bv.x);
    float o1 = fmaf(di, acc1, bv.y);
    float o2 = fmaf(di, acc2, bv.z);
    float o3 = fmaf(di, acc3, bv.w);

    if constexpr (F16OUT) {
        // relu + swizzled store: chunk q = l>>1, swizzled uint2 slot within row
        o0 = fmaxf(o0, 0.f); o1 = fmaxf(o1, 0.f);
        o2 = fmaxf(o2, 0.f); o3 = fmaxf(o3, 0.f);
        const int swz = (((l >> 1) ^ (node & 7)) << 1) | (l & 1);
        f16x4 o = {(f16)o0, (f16)o1, (f16)o2, (f16)o3};
        *reinterpret_cast<f16x4*>((f16*)outv + (size_t)node * HID + swz * 4) = o;
    } else {
        *reinterpret_cast<float4*>((float*)outv + (size_t)node * HID + l * 4) =
            make_float4(o0, o1, o2, o3);
    }
}

// ================= launch =================

extern "C" void kernel_launch(void* const* d_in, const int* in_sizes, int n_in,
                              void* d_out, int out_size, void* d_ws, size_t ws_size,
                              hipStream_t stream) {
    const float* x  = (const float*)d_in[0];
    const int*   ei = (const int*)  d_in[1];
    const float* W0 = (const float*)d_in[2];
    const float* b0 = (const float*)d_in[3];
    const float* W1 = (const float*)d_in[4];
    const float* b1 = (const float*)d_in[5];
    const float* W2 = (const float*)d_in[6];
    const float* b2 = (const float*)d_in[7];

    const int N = in_sizes[0] / HID;
    const int E = in_sizes[1] / 2;
    const int* row = ei;        // sources
    const int* col = ei + E;    // destinations

    const int nb_n = (N + 255) / 256;

    // workspace layout
    f16*   h16     = (f16*)d_ws;                      // [N,128] f16 (= h', dinv-scaled)
    float* dinv    = (float*)(h16 + (size_t)N * HID); // [N]
    int*   cnt     = (int*)(dinv + N);                // [N]
    int*   row_ptr = cnt + N;                         // [N+1]
    int*   fill    = row_ptr + (N + 1);               // [N]
    int*   bsum    = fill + N;                        // [nb_n]
    int*   csr_src = bsum + nb_n;                     // [E]
    f16*   wt      = (f16*)(csr_src + E);             // [3*32768]
    f16*   wt0     = wt;
    f16*   wt1     = wt + 32768;
    f16*   wt2     = wt + 65536;
    f16*   act     = (f16*)d_out;                     // layers 0,1 activation (f16, swizzled, relu'd)
    float* out     = (float*)d_out;                   // final f32 output

    const int nb_gemm = (N + BR - 1) / BR;
    const int nb_agg  = (N + 7) / 8;                  // 2 nodes per wave
    const int nb_fill = ((E + FILL_CHUNK - 1) / FILL_CHUNK) * 8;

    // ---- CSR build + W prep ----
    hipMemsetAsync(cnt, 0, (size_t)N * sizeof(int), stream);
    k_wprep3<<<48, 256, 0, stream>>>(W0, W1, W2, wt);
    k_deg_count <<<nb_fill, 256, 0, stream>>>(col, cnt, E, N);
    k_scan_block<<<nb_n, 256, 0, stream>>>(cnt, row_ptr, bsum, dinv, N);
    k_scan_bsum <<<1, 1024, 0, stream>>>(bsum, nb_n);
    k_scan_add  <<<nb_n, 256, 0, stream>>>(row_ptr, bsum, fill, N, E);
    k_fill      <<<nb_fill, 256, 0, stream>>>(row, col, fill, csr_src, E, N);

    // ---- layer 0: x (f32) -> h16 -> act (f16, swizzled+relu) ----
    k_gemm<0>      <<<nb_gemm, 512, 0, stream>>>(x, wt0, dinv, h16, N);
    k_agg_csr<true><<<nb_agg, 256, 0, stream>>>(h16, csr_src, row_ptr, dinv, b0, act, N);
    // ---- layer 1: act -> h16 -> act ----
    k_gemm<1>      <<<nb_gemm, 512, 0, stream>>>(act, wt1, dinv, h16, N);
    k_agg_csr<true><<<nb_agg, 256, 0, stream>>>(h16, csr_src, row_ptr, dinv, b1, act, N);
    // ---- layer 2: act -> h16 -> out (f32) ----
    k_gemm<1>      <<<nb_gemm, 512, 0, stream>>>(act, wt2, dinv, h16, N);
    k_agg_csr<false><<<nb_agg, 256, 0, stream>>>(h16, csr_src, row_ptr, dinv, b2, out, N);
}